// Round 9
// baseline (512.502 us; speedup 1.0000x reference)
//
#include <hip/hip_runtime.h>
#include <math.h>

#define TWO_PI 6.28318530717958647692f

typedef float f4 __attribute__((ext_vector_type(4)));

#define NBLK 512u

// Software grid barrier. RELAXED polls (no per-poll cache invalidate);
// release/acquire via __threadfence() at the edges only.
// Deadlock-safe: LDS 35.25KB + VGPR<=256 => capacity >=4 blocks/CU =>
// 512 blocks always co-resident regardless of packing.
__device__ __forceinline__ void gbar(unsigned* cnt, unsigned target) {
    __syncthreads();
    __threadfence();                       // release my block's writes
    if (threadIdx.x == 0) {
        atomicAdd(cnt, 1u);                // device scope
        while (__hip_atomic_load(cnt, __ATOMIC_RELAXED,
                                 __HIP_MEMORY_SCOPE_AGENT) < target)
            __builtin_amdgcn_s_sleep(8);
    }
    __syncthreads();
    __threadfence();                       // acquire: drop stale lines
}

// ---------------------------------------------------------------------------
// Front mega: P1 gather, P2 grouped conv, P3 projection, P4 attention map.
// 512 blocks x 256 threads, 3 software grid barriers, LDS union 9024 floats.
// ---------------------------------------------------------------------------
__global__ __launch_bounds__(256, 2) void front(
        const float* __restrict__ x,
        const float* __restrict__ w_polar,
        const float* __restrict__ b_polar,
        const float* __restrict__ w_attn1,
        const float* __restrict__ b_attn1,
        const float* __restrict__ w_attn2,
        const float* __restrict__ b_attn2,
        float* __restrict__ pf,
        float* __restrict__ pp_t,
        float* __restrict__ q,
        float* __restrict__ att,
        unsigned* __restrict__ barcnt) {
    __shared__ __align__(16) float sp[9024];     // 35.25 KB, reused per phase
    int tid = threadIdx.x;
    int blk = blockIdx.x;

    // ---------------- P1: cartesian -> polar gather (524288 outputs) -------
    {
        float* w00s = sp;        float* w01s = sp + 128;
        float* w10s = sp + 256;  float* w11s = sp + 384;
        int*   o00s = (int*)(sp + 512);  int* o01s = (int*)(sp + 640);
        int*   o10s = (int*)(sp + 768);  int* o11s = (int*)(sp + 896);
        if (tid < 128) {
            int a = tid >> 3, r = tid & 7;
            float theta = (TWO_PI * (float)a) / 16.0f;
            float rad   = ((float)r + 0.5f) / 8.0f * 64.0f;
            float ys = 63.5f + rad * sinf(theta);
            float xs = 63.5f + rad * cosf(theta);
            float y0 = floorf(ys), x0 = floorf(xs);
            float wy = ys - y0,    wx = xs - x0;
            int y0i = min(max((int)y0, 0), 127);
            int y1i = min(max((int)y0 + 1, 0), 127);
            int x0i = min(max((int)x0, 0), 127);
            int x1i = min(max((int)x0 + 1, 0), 127);
            float valid = (ys >= 0.0f && ys <= 127.0f && xs >= 0.0f && xs <= 127.0f) ? 1.0f : 0.0f;
            w00s[tid] = valid * (1.0f - wy) * (1.0f - wx);
            w01s[tid] = valid * (1.0f - wy) * wx;
            w10s[tid] = valid * wy * (1.0f - wx);
            w11s[tid] = valid * wy * wx;
            o00s[tid] = y0i * 128 + x0i;
            o01s[tid] = y0i * 128 + x1i;
            o10s[tid] = y1i * 128 + x0i;
            o11s[tid] = y1i * 128 + x1i;
        }
        __syncthreads();
        int bin = tid & 127;
        float W0 = w00s[bin], W1 = w01s[bin], W2 = w10s[bin], W3 = w11s[bin];
        int O0 = o00s[bin], O1 = o01s[bin], O2 = o10s[bin], O3 = o11s[bin];
        #pragma unroll
        for (int j = 0; j < 4; ++j) {
            int t = blk * 1024 + j * 256 + tid;    // < 524288
            int img = t >> 7;
            const float* ib = x + ((size_t)img << 14);
            pf[t] = ib[O0] * W0 + ib[O1] * W1 + ib[O2] * W2 + ib[O3] * W3;
        }
    }
    gbar(barcnt, 1 * NBLK);

    // ---------------- P2: grouped 3x3 conv, pp_t[b][bin][oc] ---------------
    // One role per block. Two staging passes of 32 ic (22.5 KB each);
    // within a pass the two thread-halves take 16 ic each; LDS reduce at end.
    {
        float* pfs = sp;            // 32*180 floats, halo-padded
        float* red = sp + 5760;     // 128*8
        int b  = blk >> 5;
        int g  = (blk >> 3) & 3;
        int ot = blk & 7;
        for (int i = tid; i < 32 * 180; i += 256) pfs[i] = 0.0f;
        __syncthreads();
        int half = tid >> 7;
        int bt   = tid & 127;
        int a = bt >> 3, r = bt & 7;
        int oc0 = g * 64 + ot * 8;
        float acc[8];
        #pragma unroll
        for (int j = 0; j < 8; ++j) acc[j] = 0.0f;
        const float* src = pf + ((size_t)(b * 256 + g * 64) << 7);

        for (int pass = 0; pass < 2; ++pass) {
            for (int i = tid; i < 4096; i += 256) {
                int icl = i >> 7, bin = i & 127;
                pfs[icl * 180 + ((bin >> 3) + 1) * 10 + (bin & 7) + 1]
                    = src[pass * 4096 + i];
            }
            __syncthreads();
            const float* wbase = w_polar + (size_t)oc0 * 576 + pass * 288 + half * 144;
            const float* pbase = pfs + half * 16 * 180 + a * 10 + r;
            for (int ic = 0; ic < 16; ++ic) {
                float v[9];
                const float* base = pbase + ic * 180;
                #pragma unroll
                for (int dh = 0; dh < 3; ++dh)
                    #pragma unroll
                    for (int dw = 0; dw < 3; ++dw)
                        v[dh * 3 + dw] = base[dh * 10 + dw];
                #pragma unroll
                for (int j = 0; j < 8; ++j) {
                    const float* wp = wbase + j * 576 + ic * 9;
                    acc[j] += wp[0]*v[0] + wp[1]*v[1] + wp[2]*v[2]
                            + wp[3]*v[3] + wp[4]*v[4] + wp[5]*v[5]
                            + wp[6]*v[6] + wp[7]*v[7] + wp[8]*v[8];
                }
            }
            __syncthreads();    // before restaging / reduce reuse
        }
        if (half) {
            #pragma unroll
            for (int j = 0; j < 8; ++j) red[bt * 8 + j] = acc[j];
        }
        __syncthreads();
        if (!half) {
            float* dst = pp_t + ((size_t)((b << 7) + bt)) * 256 + oc0;
            #pragma unroll
            for (int j = 0; j < 8; ++j)
                dst[j] = acc[j] + red[bt * 8 + j] + b_polar[oc0 + j];
        }
    }
    gbar(barcnt, 2 * NBLK);

    // ---------------- P3: q[b][bin][o] = W1 . pp_t row ---------------------
    // Two passes of 128 c (32 KB swizzled W1-half each).
    {
        float* wl = sp;             // 8192 floats, XOR-swizzled [cl][o]
        int n = blk * 256 + tid;    // exactly covers 131072
        int b   = n >> 13;
        int bin = (n >> 6) & 127;
        int o   = n & 63;
        const float* prow = pp_t + ((size_t)((b << 7) + bin)) * 256;
        float acc = 0.0f;
        for (int pass = 0; pass < 2; ++pass) {
            for (int f = tid; f < 8192; f += 256) {     // f = o*128 + cl
                int oo = f >> 7, cl = f & 127;
                wl[(cl << 6) + (oo ^ (cl & 31))] = w_attn1[oo * 256 + pass * 128 + cl];
            }
            __syncthreads();
            const float4* pr4 = (const float4*)(prow + pass * 128);
            #pragma unroll 8
            for (int c4 = 0; c4 < 32; ++c4) {
                float4 p = pr4[c4];
                int c = c4 << 2;
                acc += wl[( c      << 6) + (o ^ ( c      & 31))] * p.x;
                acc += wl[((c + 1) << 6) + (o ^ ((c + 1) & 31))] * p.y;
                acc += wl[((c + 2) << 6) + (o ^ ((c + 2) & 31))] * p.z;
                acc += wl[((c + 3) << 6) + (o ^ ((c + 3) & 31))] * p.w;
            }
            __syncthreads();
        }
        q[n] = acc;
    }
    gbar(barcnt, 3 * NBLK);

    // ---------------- P4: attention map (2 px/thread) ----------------------
    {
        float* qs  = sp;            // 8896 swizzled
        float* b1s = sp + 8896;
        float* w2s = sp + 8960;
        int b    = blk >> 5;
        int tile = blk & 31;
        const float* qb = q + ((size_t)b << 13);
        for (int i = tid; i < 8192; i += 256) {
            int bin = i >> 6, o = i & 63;
            qs[(bin >> 3) * 556 + (bin & 7) * 68 + o] = qb[i];
        }
        if (tid < 64) { b1s[tid] = b_attn1[tid]; w2s[tid] = w_attn2[tid]; }
        __syncthreads();
        float b2 = b_attn2[0];
        const float4* q4  = (const float4*)qs;
        const float4* b14 = (const float4*)b1s;
        const float4* w24 = (const float4*)w2s;
        #pragma unroll
        for (int k = 0; k < 2; ++k) {
            int p = (tile << 9) + (k << 8) + tid;
            int h = p >> 7, w = p & 127;
            float dy = (float)h - 63.5f;
            float dx = (float)w - 63.5f;
            float rr = sqrtf(dy * dy + dx * dx);
            float th = atan2f(dy, dx);
            if (th < 0.0f) th += TWO_PI;
            float aa = th / TWO_PI * 16.0f;
            float a0 = floorf(aa);
            float wa = aa - a0;
            int ia0 = ((int)a0) & 15;
            int ia1 = (ia0 + 1) & 15;
            float ri = rr / 64.0f * 8.0f - 0.5f;
            float r0 = floorf(ri);
            float wr = ri - r0;
            int ir0 = (int)fminf(fmaxf(r0, 0.0f), 7.0f);
            int ir1 = (int)fminf(fmaxf(r0 + 1.0f, 0.0f), 7.0f);
            float valid = (rr <= 64.0f) ? 1.0f : 0.0f;
            float w00 = valid * (1.0f - wa) * (1.0f - wr);
            float w01 = valid * (1.0f - wa) * wr;
            float w10 = valid * wa * (1.0f - wr);
            float w11 = valid * wa * wr;
            int t00 = ia0 * 139 + ir0 * 17;
            int t01 = ia0 * 139 + ir1 * 17;
            int t10 = ia1 * 139 + ir0 * 17;
            int t11 = ia1 * 139 + ir1 * 17;
            float acc = b2;
            #pragma unroll
            for (int i = 0; i < 16; ++i) {
                float4 v00 = q4[t00 + i], v01 = q4[t01 + i];
                float4 v10 = q4[t10 + i], v11 = q4[t11 + i];
                float4 bb = b14[i], ww = w24[i];
                float sx = w00 * v00.x + w01 * v01.x + w10 * v10.x + w11 * v11.x;
                float sy = w00 * v00.y + w01 * v01.y + w10 * v10.y + w11 * v11.y;
                float sz = w00 * v00.z + w01 * v01.z + w10 * v10.z + w11 * v11.z;
                float sw = w00 * v00.w + w01 * v01.w + w10 * v10.w + w11 * v11.w;
                acc += fmaxf(sx + bb.x, 0.0f) * ww.x;
                acc += fmaxf(sy + bb.y, 0.0f) * ww.y;
                acc += fmaxf(sz + bb.z, 0.0f) * ww.z;
                acc += fmaxf(sw + bb.w, 0.0f) * ww.w;
            }
            att[((size_t)b << 14) + p] = 1.0f / (1.0f + __expf(-acc));
        }
    }
}

// ---------------------------------------------------------------------------
// K4b: out = x * att. r3-exact best-measured config: grid-stride, NT, 2048 blk.
// ---------------------------------------------------------------------------
__global__ __launch_bounds__(256) void k4b_mul(const f4* __restrict__ x4,
                                               const float* __restrict__ att,
                                               f4* __restrict__ out4) {
    const f4* att4 = (const f4*)att;
    int idx = blockIdx.x * 256 + threadIdx.x;
    int stride = gridDim.x * 256;
    for (int i = idx; i < 16777216; i += stride) {
        f4 xv = __builtin_nontemporal_load(&x4[i]);
        f4 av = att4[((i >> 20) << 12) | (i & 4095)];
        __builtin_nontemporal_store(xv * av, &out4[i]);
    }
}

// ---------------------------------------------------------------------------
extern "C" void kernel_launch(void* const* d_in, const int* in_sizes, int n_in,
                              void* d_out, int out_size, void* d_ws, size_t ws_size,
                              hipStream_t stream) {
    const float* x       = (const float*)d_in[0];
    const float* w_polar = (const float*)d_in[1];
    const float* b_polar = (const float*)d_in[2];
    const float* w_attn1 = (const float*)d_in[3];
    const float* b_attn1 = (const float*)d_in[4];
    const float* w_attn2 = (const float*)d_in[5];
    const float* b_attn2 = (const float*)d_in[6];
    float* out = (float*)d_out;
    float* ws  = (float*)d_ws;

    float*    pf     = ws;                 // 524288 f  [b][c][a][r]
    float*    pp_t   = ws + 524288;        // 524288 f  [b][bin][c]
    float*    q      = ws + 1048576;       // 131072 f  [b][bin][o]
    float*    att    = ws + 1179648;       // 262144 f  [b][h][w]
    unsigned* barcnt = (unsigned*)(ws + 1572864);

    hipMemsetAsync((void*)barcnt, 0, 64, stream);
    hipLaunchKernelGGL(front, dim3(NBLK), dim3(256), 0, stream,
                       x, w_polar, b_polar, w_attn1, b_attn1, w_attn2, b_attn2,
                       pf, pp_t, q, att, barcnt);
    hipLaunchKernelGGL(k4b_mul, dim3(2048), dim3(256), 0, stream,
                       (const f4*)x, att, (f4*)out);
}

// Round 10
// 281.781 us; speedup vs baseline: 1.8188x; 1.8188x over previous
//
#include <hip/hip_runtime.h>
#include <math.h>

#define TWO_PI 6.28318530717958647692f

typedef float f4 __attribute__((ext_vector_type(4)));

// ---------------------------------------------------------------------------
// K12 fused: polar gather + grouped 3x3 conv, one block per (batch, group).
// 64 blocks x 1024 threads. Gathers its 64 channels of x straight into the
// halo-padded LDS tile (no pf round-trip), then the proven conv body:
// 8 oc-slots x 128 bins, weights via wave-uniform scalar loads.
// Taps: all interior (rad<=60 -> ys,xs in [3.5,123.5]), so no clamp/valid
// (verified passing in r5).  Output transposed: pp_t[b][bin][oc].
// ---------------------------------------------------------------------------
__global__ __launch_bounds__(1024, 1) void k12_fused(const float* __restrict__ x,
                                                     const float* __restrict__ w_polar,
                                                     const float* __restrict__ b_polar,
                                                     float* __restrict__ pp_t) {
    __shared__ float w0s[128], w1s[128], w2s[128], w3s[128];
    __shared__ int   o0s[128];
    __shared__ __align__(16) float pfs[64 * 180];   // [ic][a+halo][r+halo]
    int tid = threadIdx.x;
    int b = blockIdx.x >> 2;
    int g = blockIdx.x & 3;

    if (tid < 128) {
        int a = tid >> 3, r = tid & 7;
        float theta = (TWO_PI * (float)a) / 16.0f;
        float rad   = ((float)r + 0.5f) * 8.0f;
        float ys = 63.5f + rad * sinf(theta);
        float xs = 63.5f + rad * cosf(theta);
        float y0 = floorf(ys), x0 = floorf(xs);
        float wy = ys - y0,    wx = xs - x0;
        w0s[tid] = (1.0f - wy) * (1.0f - wx);
        w1s[tid] = (1.0f - wy) * wx;
        w2s[tid] = wy * (1.0f - wx);
        w3s[tid] = wy * wx;
        o0s[tid] = (int)y0 * 128 + (int)x0;
    }
    for (int i = tid; i < 64 * 180; i += 1024) pfs[i] = 0.0f;
    __syncthreads();

    // gather: 8 staged elements per thread, 4 taps each (32 loads in flight)
    for (int i = tid; i < 8192; i += 1024) {
        int ic = i >> 7, bin = i & 127;
        const float* ib = x + ((size_t)(b * 256 + g * 64 + ic) << 14);
        int o = o0s[bin];
        float v = ib[o]       * w0s[bin] + ib[o + 1]   * w1s[bin]
                + ib[o + 128] * w2s[bin] + ib[o + 129] * w3s[bin];
        pfs[ic * 180 + ((bin >> 3) + 1) * 10 + (bin & 7) + 1] = v;
    }
    __syncthreads();

    // conv: slot = tid>>7 (0..7) -> 8 output channels; bin = tid&127
    int slot = tid >> 7;
    int bt   = tid & 127;
    int a = bt >> 3, r = bt & 7;
    int oc0 = g * 64 + slot * 8;
    float acc[8];
    #pragma unroll
    for (int j = 0; j < 8; ++j) acc[j] = 0.0f;

    const float* wbase = w_polar + (size_t)oc0 * 576;   // + j*576 + ic*9
    const float* pbase = pfs + a * 10 + r;
    for (int ic = 0; ic < 64; ++ic) {
        float v[9];
        const float* base = pbase + ic * 180;
        #pragma unroll
        for (int dh = 0; dh < 3; ++dh)
            #pragma unroll
            for (int dw = 0; dw < 3; ++dw)
                v[dh * 3 + dw] = base[dh * 10 + dw];
        #pragma unroll
        for (int j = 0; j < 8; ++j) {
            const float* wp = wbase + j * 576 + ic * 9;
            acc[j] += wp[0]*v[0] + wp[1]*v[1] + wp[2]*v[2]
                    + wp[3]*v[3] + wp[4]*v[4] + wp[5]*v[5]
                    + wp[6]*v[6] + wp[7]*v[7] + wp[8]*v[8];
        }
    }
    float* dst = pp_t + ((size_t)(b * 128 + bt)) * 256 + oc0;
    #pragma unroll
    for (int j = 0; j < 8; ++j) dst[j] = acc[j] + b_polar[oc0 + j];
}

// ---------------------------------------------------------------------------
// K3: q[b][bin][o] = sum_c w_attn1[o][c] * pp_t[b][bin][c]   (r3-exact)
// ---------------------------------------------------------------------------
__global__ __launch_bounds__(256) void k3_proj(const float* __restrict__ pp_t,
                                               const float* __restrict__ w_attn1,
                                               float* __restrict__ q) {
    __shared__ __align__(16) float wl[16384];
    int tid = threadIdx.x;
    for (int i = tid; i < 16384; i += 256) {       // i = o*256 + c
        int o = i >> 8, c = i & 255;
        wl[(c << 6) + (o ^ (c & 31))] = w_attn1[i];
    }
    __syncthreads();
    int n = blockIdx.x * 256 + tid;     // < 131072
    int b   = n >> 13;
    int bin = (n >> 6) & 127;
    int o   = n & 63;
    const float4* pr4 = (const float4*)(pp_t + ((size_t)((b << 7) + bin)) * 256);
    float acc = 0.0f;
    #pragma unroll 8
    for (int c4 = 0; c4 < 64; ++c4) {
        float4 p = pr4[c4];
        int c = c4 << 2;
        acc += wl[( c      << 6) + (o ^ ( c      & 31))] * p.x;
        acc += wl[((c + 1) << 6) + (o ^ ((c + 1) & 31))] * p.y;
        acc += wl[((c + 2) << 6) + (o ^ ((c + 2) & 31))] * p.z;
        acc += wl[((c + 3) << 6) + (o ^ ((c + 3) & 31))] * p.w;
    }
    q[n] = acc;
}

// ---------------------------------------------------------------------------
// K4a: attention map att[b][h][w]. 1024 blocks, 1 px/thread.  (r3-exact)
// ---------------------------------------------------------------------------
__global__ __launch_bounds__(256) void k4a_att(const float* __restrict__ q,
                                               const float* __restrict__ b_attn1,
                                               const float* __restrict__ w_attn2,
                                               const float* __restrict__ b_attn2,
                                               float* __restrict__ att) {
    __shared__ __align__(16) float qs[8896];
    __shared__ __align__(16) float b1s[64];
    __shared__ __align__(16) float w2s[64];
    int b    = blockIdx.x >> 6;
    int tile = blockIdx.x & 63;
    int tid  = threadIdx.x;
    const float* qb = q + ((size_t)b << 13);
    for (int i = tid; i < 8192; i += 256) {
        int bin = i >> 6, o = i & 63;
        qs[(bin >> 3) * 556 + (bin & 7) * 68 + o] = qb[i];
    }
    if (tid < 64) { b1s[tid] = b_attn1[tid]; w2s[tid] = w_attn2[tid]; }
    __syncthreads();
    float b2 = b_attn2[0];
    const float4* q4  = (const float4*)qs;
    const float4* b14 = (const float4*)b1s;
    const float4* w24 = (const float4*)w2s;

    int p = (tile << 8) + tid;
    int h = p >> 7, w = p & 127;
    float dy = (float)h - 63.5f;
    float dx = (float)w - 63.5f;
    float rr = sqrtf(dy * dy + dx * dx);
    float th = atan2f(dy, dx);
    if (th < 0.0f) th += TWO_PI;
    float aa = th / TWO_PI * 16.0f;
    float a0 = floorf(aa);
    float wa = aa - a0;
    int ia0 = ((int)a0) & 15;
    int ia1 = (ia0 + 1) & 15;
    float ri = rr / 64.0f * 8.0f - 0.5f;
    float r0 = floorf(ri);
    float wr = ri - r0;
    int ir0 = (int)fminf(fmaxf(r0, 0.0f), 7.0f);
    int ir1 = (int)fminf(fmaxf(r0 + 1.0f, 0.0f), 7.0f);
    float valid = (rr <= 64.0f) ? 1.0f : 0.0f;
    float w00 = valid * (1.0f - wa) * (1.0f - wr);
    float w01 = valid * (1.0f - wa) * wr;
    float w10 = valid * wa * (1.0f - wr);
    float w11 = valid * wa * wr;
    int t00 = ia0 * 139 + ir0 * 17;
    int t01 = ia0 * 139 + ir1 * 17;
    int t10 = ia1 * 139 + ir0 * 17;
    int t11 = ia1 * 139 + ir1 * 17;
    float acc = b2;
    #pragma unroll
    for (int i = 0; i < 16; ++i) {
        float4 v00 = q4[t00 + i], v01 = q4[t01 + i];
        float4 v10 = q4[t10 + i], v11 = q4[t11 + i];
        float4 bb = b14[i], ww = w24[i];
        float sx = w00 * v00.x + w01 * v01.x + w10 * v10.x + w11 * v11.x;
        float sy = w00 * v00.y + w01 * v01.y + w10 * v10.y + w11 * v11.y;
        float sz = w00 * v00.z + w01 * v01.z + w10 * v10.z + w11 * v11.z;
        float sw = w00 * v00.w + w01 * v01.w + w10 * v10.w + w11 * v11.w;
        acc += fmaxf(sx + bb.x, 0.0f) * ww.x;
        acc += fmaxf(sy + bb.y, 0.0f) * ww.y;
        acc += fmaxf(sz + bb.z, 0.0f) * ww.z;
        acc += fmaxf(sw + bb.w, 0.0f) * ww.w;
    }
    float attv = 1.0f / (1.0f + __expf(-acc));
    att[((size_t)b << 14) + p] = attv;
}

// ---------------------------------------------------------------------------
// K4b: out = x * att. r3-exact: grid-stride, NT load/store, 2048 blocks.
// ---------------------------------------------------------------------------
__global__ __launch_bounds__(256) void k4b_mul(const f4* __restrict__ x4,
                                               const float* __restrict__ att,
                                               f4* __restrict__ out4) {
    const f4* att4 = (const f4*)att;
    int idx = blockIdx.x * 256 + threadIdx.x;
    int stride = gridDim.x * 256;
    for (int i = idx; i < 16777216; i += stride) {
        f4 xv = __builtin_nontemporal_load(&x4[i]);
        f4 av = att4[((i >> 20) << 12) | (i & 4095)];
        __builtin_nontemporal_store(xv * av, &out4[i]);
    }
}

// ---------------------------------------------------------------------------
extern "C" void kernel_launch(void* const* d_in, const int* in_sizes, int n_in,
                              void* d_out, int out_size, void* d_ws, size_t ws_size,
                              hipStream_t stream) {
    const float* x       = (const float*)d_in[0];
    const float* w_polar = (const float*)d_in[1];
    const float* b_polar = (const float*)d_in[2];
    const float* w_attn1 = (const float*)d_in[3];
    const float* b_attn1 = (const float*)d_in[4];
    const float* w_attn2 = (const float*)d_in[5];
    const float* b_attn2 = (const float*)d_in[6];
    float* out = (float*)d_out;
    float* ws  = (float*)d_ws;

    float* pp_t = ws;                 // 524288 f  [b][bin][c]
    float* q    = ws + 524288;        // 131072 f  [b][bin][o]
    float* att  = ws + 655360;        // 262144 f  [b][h][w]

    hipLaunchKernelGGL(k12_fused, dim3(64),   dim3(1024), 0, stream,
                       x, w_polar, b_polar, pp_t);
    hipLaunchKernelGGL(k3_proj,   dim3(512),  dim3(256), 0, stream, pp_t, w_attn1, q);
    hipLaunchKernelGGL(k4a_att,   dim3(1024), dim3(256), 0, stream,
                       q, b_attn1, w_attn2, b_attn2, att);
    hipLaunchKernelGGL(k4b_mul,   dim3(2048), dim3(256), 0, stream,
                       (const f4*)x, att, (f4*)out);
}

// Round 11
// 160.626 us; speedup vs baseline: 3.1906x; 1.7543x over previous
//
#include <hip/hip_runtime.h>
#include <math.h>

#define TWO_PI 6.28318530717958647692f

typedef float f4 __attribute__((ext_vector_type(4)));

// ---------------------------------------------------------------------------
// K1: cartesian -> polar sampling.  pf[b][c][a][r], one thread per element.
// 128 distinct sample points -> tap table (SoA LDS) built once per block.
// (r3-exact, measured-best form.)
// ---------------------------------------------------------------------------
__global__ __launch_bounds__(256) void k1_cart2polar(const float* __restrict__ x,
                                                     float* __restrict__ pf) {
    __shared__ float w00s[128], w01s[128], w10s[128], w11s[128];
    __shared__ int   o00s[128], o01s[128], o10s[128], o11s[128];
    int tid = threadIdx.x;
    if (tid < 128) {
        int a = tid >> 3, r = tid & 7;
        float theta = (TWO_PI * (float)a) / 16.0f;
        float rad   = ((float)r + 0.5f) / 8.0f * 64.0f;
        float ys = 63.5f + rad * sinf(theta);
        float xs = 63.5f + rad * cosf(theta);
        float y0 = floorf(ys), x0 = floorf(xs);
        float wy = ys - y0,    wx = xs - x0;
        int y0i = min(max((int)y0, 0), 127);
        int y1i = min(max((int)y0 + 1, 0), 127);
        int x0i = min(max((int)x0, 0), 127);
        int x1i = min(max((int)x0 + 1, 0), 127);
        float valid = (ys >= 0.0f && ys <= 127.0f && xs >= 0.0f && xs <= 127.0f) ? 1.0f : 0.0f;
        w00s[tid] = valid * (1.0f - wy) * (1.0f - wx);
        w01s[tid] = valid * (1.0f - wy) * wx;
        w10s[tid] = valid * wy * (1.0f - wx);
        w11s[tid] = valid * wy * wx;
        o00s[tid] = y0i * 128 + x0i;
        o01s[tid] = y0i * 128 + x1i;
        o10s[tid] = y1i * 128 + x0i;
        o11s[tid] = y1i * 128 + x1i;
    }
    __syncthreads();
    int t = blockIdx.x * 256 + tid;     // < 524288
    int bin = t & 127;
    int img = t >> 7;                   // b*256 + c
    const float* ib = x + ((size_t)img << 14);
    float v = ib[o00s[bin]] * w00s[bin]
            + ib[o01s[bin]] * w01s[bin]
            + ib[o10s[bin]] * w10s[bin]
            + ib[o11s[bin]] * w11s[bin];
    pf[t] = v;
}

// ---------------------------------------------------------------------------
// K2: grouped 3x3 conv over (A=16, R=8), pad 1, groups=4.
// NEW: inner loop is LDS-only. 512 blocks (b,g,ot) x 128 threads (1/bin).
// Two ic-passes of 32: stage pf sub-tile (22.5 KB) + weight slab transposed
// to [ic][tap][oc8] (9 KB, read as uniform float4 broadcasts).
// Output transposed: pp_t[b][bin][oc].
// ---------------------------------------------------------------------------
__global__ __launch_bounds__(128) void k2_conv(const float* __restrict__ pf,
                                               const float* __restrict__ w_polar,
                                               const float* __restrict__ b_polar,
                                               float* __restrict__ pp_t) {
    __shared__ __align__(16) float pfs[32 * 180];   // [icl][a+halo][r+halo]
    __shared__ __align__(16) float wls[32 * 72];    // [icl][tap][j]
    int bid = blockIdx.x;               // 512
    int b  = bid >> 5;
    int g  = (bid >> 3) & 3;
    int ot = bid & 7;
    int tid = threadIdx.x;              // 0..127 = bin
    int a = tid >> 3, r = tid & 7;
    int oc0 = g * 64 + ot * 8;

    for (int i = tid; i < 32 * 180; i += 128) pfs[i] = 0.0f;   // halo stays 0
    __syncthreads();

    float acc[8];
    #pragma unroll
    for (int j = 0; j < 8; ++j) acc[j] = 0.0f;
    const float* src = pf + ((size_t)(b * 256 + g * 64) << 7);

    for (int pass = 0; pass < 2; ++pass) {
        // stage pf sub-tile (interior only; halo cells remain zero)
        for (int i = tid; i < 4096; i += 128) {
            int icl = i >> 7, bin = i & 127;
            pfs[icl * 180 + ((bin >> 3) + 1) * 10 + (bin & 7) + 1]
                = src[pass * 4096 + i];
        }
        // stage weights transposed: wls[icl*72 + tap*8 + j]
        for (int i = tid; i < 2304; i += 128) {
            int icl = i / 72, rem = i - icl * 72;
            int tap = rem >> 3, j = rem & 7;
            wls[i] = w_polar[(size_t)(oc0 + j) * 576 + (pass * 32 + icl) * 9 + tap];
        }
        __syncthreads();

        const float* pbase = pfs + a * 10 + r;
        for (int ic = 0; ic < 32; ++ic) {
            float v[9];
            const float* base = pbase + ic * 180;
            #pragma unroll
            for (int dh = 0; dh < 3; ++dh)
                #pragma unroll
                for (int dw = 0; dw < 3; ++dw)
                    v[dh * 3 + dw] = base[dh * 10 + dw];
            const f4* wrow = (const f4*)(wls + ic * 72);
            #pragma unroll
            for (int tap = 0; tap < 9; ++tap) {
                f4 wlo = wrow[tap * 2];
                f4 whi = wrow[tap * 2 + 1];
                float vt = v[tap];
                acc[0] += wlo.x * vt;  acc[1] += wlo.y * vt;
                acc[2] += wlo.z * vt;  acc[3] += wlo.w * vt;
                acc[4] += whi.x * vt;  acc[5] += whi.y * vt;
                acc[6] += whi.z * vt;  acc[7] += whi.w * vt;
            }
        }
        __syncthreads();    // before restaging
    }
    float* dst = pp_t + ((size_t)(b * 128 + tid)) * 256 + oc0;
    #pragma unroll
    for (int j = 0; j < 8; ++j) dst[j] = acc[j] + b_polar[oc0 + j];
}

// ---------------------------------------------------------------------------
// K3: q[b][bin][o] = sum_c w_attn1[o][c] * pp_t[b][bin][c]   (r3-exact)
// ---------------------------------------------------------------------------
__global__ __launch_bounds__(256) void k3_proj(const float* __restrict__ pp_t,
                                               const float* __restrict__ w_attn1,
                                               float* __restrict__ q) {
    __shared__ __align__(16) float wl[16384];
    int tid = threadIdx.x;
    for (int i = tid; i < 16384; i += 256) {       // i = o*256 + c
        int o = i >> 8, c = i & 255;
        wl[(c << 6) + (o ^ (c & 31))] = w_attn1[i];
    }
    __syncthreads();
    int n = blockIdx.x * 256 + tid;     // < 131072
    int b   = n >> 13;
    int bin = (n >> 6) & 127;
    int o   = n & 63;
    const float4* pr4 = (const float4*)(pp_t + ((size_t)((b << 7) + bin)) * 256);
    float acc = 0.0f;
    #pragma unroll 8
    for (int c4 = 0; c4 < 64; ++c4) {
        float4 p = pr4[c4];
        int c = c4 << 2;
        acc += wl[( c      << 6) + (o ^ ( c      & 31))] * p.x;
        acc += wl[((c + 1) << 6) + (o ^ ((c + 1) & 31))] * p.y;
        acc += wl[((c + 2) << 6) + (o ^ ((c + 2) & 31))] * p.z;
        acc += wl[((c + 3) << 6) + (o ^ ((c + 3) & 31))] * p.w;
    }
    q[n] = acc;
}

// ---------------------------------------------------------------------------
// K4a: attention map att[b][h][w]. 1024 blocks, 1 px/thread.  (r3-exact)
// ---------------------------------------------------------------------------
__global__ __launch_bounds__(256) void k4a_att(const float* __restrict__ q,
                                               const float* __restrict__ b_attn1,
                                               const float* __restrict__ w_attn2,
                                               const float* __restrict__ b_attn2,
                                               float* __restrict__ att) {
    __shared__ __align__(16) float qs[8896];
    __shared__ __align__(16) float b1s[64];
    __shared__ __align__(16) float w2s[64];
    int b    = blockIdx.x >> 6;
    int tile = blockIdx.x & 63;
    int tid  = threadIdx.x;
    const float* qb = q + ((size_t)b << 13);
    for (int i = tid; i < 8192; i += 256) {
        int bin = i >> 6, o = i & 63;
        qs[(bin >> 3) * 556 + (bin & 7) * 68 + o] = qb[i];
    }
    if (tid < 64) { b1s[tid] = b_attn1[tid]; w2s[tid] = w_attn2[tid]; }
    __syncthreads();
    float b2 = b_attn2[0];
    const float4* q4  = (const float4*)qs;
    const float4* b14 = (const float4*)b1s;
    const float4* w24 = (const float4*)w2s;

    int p = (tile << 8) + tid;
    int h = p >> 7, w = p & 127;
    float dy = (float)h - 63.5f;
    float dx = (float)w - 63.5f;
    float rr = sqrtf(dy * dy + dx * dx);
    float th = atan2f(dy, dx);
    if (th < 0.0f) th += TWO_PI;
    float aa = th / TWO_PI * 16.0f;
    float a0 = floorf(aa);
    float wa = aa - a0;
    int ia0 = ((int)a0) & 15;
    int ia1 = (ia0 + 1) & 15;
    float ri = rr / 64.0f * 8.0f - 0.5f;
    float r0 = floorf(ri);
    float wr = ri - r0;
    int ir0 = (int)fminf(fmaxf(r0, 0.0f), 7.0f);
    int ir1 = (int)fminf(fmaxf(r0 + 1.0f, 0.0f), 7.0f);
    float valid = (rr <= 64.0f) ? 1.0f : 0.0f;
    float w00 = valid * (1.0f - wa) * (1.0f - wr);
    float w01 = valid * (1.0f - wa) * wr;
    float w10 = valid * wa * (1.0f - wr);
    float w11 = valid * wa * wr;
    int t00 = ia0 * 139 + ir0 * 17;
    int t01 = ia0 * 139 + ir1 * 17;
    int t10 = ia1 * 139 + ir0 * 17;
    int t11 = ia1 * 139 + ir1 * 17;
    float acc = b2;
    #pragma unroll
    for (int i = 0; i < 16; ++i) {
        float4 v00 = q4[t00 + i], v01 = q4[t01 + i];
        float4 v10 = q4[t10 + i], v11 = q4[t11 + i];
        float4 bb = b14[i], ww = w24[i];
        float sx = w00 * v00.x + w01 * v01.x + w10 * v10.x + w11 * v11.x;
        float sy = w00 * v00.y + w01 * v01.y + w10 * v10.y + w11 * v11.y;
        float sz = w00 * v00.z + w01 * v01.z + w10 * v10.z + w11 * v11.z;
        float sw = w00 * v00.w + w01 * v01.w + w10 * v10.w + w11 * v11.w;
        acc += fmaxf(sx + bb.x, 0.0f) * ww.x;
        acc += fmaxf(sy + bb.y, 0.0f) * ww.y;
        acc += fmaxf(sz + bb.z, 0.0f) * ww.z;
        acc += fmaxf(sw + bb.w, 0.0f) * ww.w;
    }
    float attv = 1.0f / (1.0f + __expf(-acc));
    att[((size_t)b << 14) + p] = attv;
}

// ---------------------------------------------------------------------------
// K4b: out = x * att. r3-exact: grid-stride, NT load/store, 2048 blocks.
// ---------------------------------------------------------------------------
__global__ __launch_bounds__(256) void k4b_mul(const f4* __restrict__ x4,
                                               const float* __restrict__ att,
                                               f4* __restrict__ out4) {
    const f4* att4 = (const f4*)att;
    int idx = blockIdx.x * 256 + threadIdx.x;
    int stride = gridDim.x * 256;
    for (int i = idx; i < 16777216; i += stride) {
        f4 xv = __builtin_nontemporal_load(&x4[i]);
        f4 av = att4[((i >> 20) << 12) | (i & 4095)];
        __builtin_nontemporal_store(xv * av, &out4[i]);
    }
}

// ---------------------------------------------------------------------------
extern "C" void kernel_launch(void* const* d_in, const int* in_sizes, int n_in,
                              void* d_out, int out_size, void* d_ws, size_t ws_size,
                              hipStream_t stream) {
    const float* x       = (const float*)d_in[0];
    const float* w_polar = (const float*)d_in[1];
    const float* b_polar = (const float*)d_in[2];
    const float* w_attn1 = (const float*)d_in[3];
    const float* b_attn1 = (const float*)d_in[4];
    const float* w_attn2 = (const float*)d_in[5];
    const float* b_attn2 = (const float*)d_in[6];
    float* out = (float*)d_out;
    float* ws  = (float*)d_ws;

    float* pf   = ws;                 // 524288 f  [b][c][a][r]
    float* pp_t = ws + 524288;        // 524288 f  [b][bin][c]
    float* q    = ws + 1048576;       // 131072 f  [b][bin][o]
    float* att  = ws + 1179648;       // 262144 f  [b][h][w]

    hipLaunchKernelGGL(k1_cart2polar, dim3(2048), dim3(256), 0, stream, x, pf);
    hipLaunchKernelGGL(k2_conv,       dim3(512),  dim3(128), 0, stream,
                       pf, w_polar, b_polar, pp_t);
    hipLaunchKernelGGL(k3_proj,       dim3(512),  dim3(256), 0, stream, pp_t, w_attn1, q);
    hipLaunchKernelGGL(k4a_att,       dim3(1024), dim3(256), 0, stream,
                       q, b_attn1, w_attn2, b_attn2, att);
    hipLaunchKernelGGL(k4b_mul,       dim3(2048), dim3(256), 0, stream,
                       (const f4*)x, att, (f4*)out);
}